// Round 3
// baseline (715084.326 us; speedup 1.0000x reference)
//
#include <hip/hip_runtime.h>
#include <math.h>

#define IN_SIZE 96
#define HID 128
#define H3 384
#define LIN_IN 32

// ---------------------------------------------------------------------------
// Kernel A (parallel): igates[t][j] = dot(input_GRU[t,:], w_ih[j,:]) + b_ih[j]
// ---------------------------------------------------------------------------
__global__ __launch_bounds__(384, 2)
void igates_kernel(const float* __restrict__ x, const float* __restrict__ w_ih,
                   const float* __restrict__ b_ih, float* __restrict__ ig, int T)
{
    const int TT = 16;
    int t0 = blockIdx.x * TT;
    int j = threadIdx.x; // 0..383
    __shared__ __align__(16) float xs[TT * IN_SIZE]; // 6 KB
    for (int idx = j; idx < TT * IN_SIZE; idx += H3)
        xs[idx] = x[(size_t)t0 * IN_SIZE + idx];
    __syncthreads();

    float acc[TT];
    float b = b_ih[j];
#pragma unroll
    for (int tt = 0; tt < TT; tt++) acc[tt] = b;

    const float4* w4 = (const float4*)(w_ih + (size_t)j * IN_SIZE);
#pragma unroll
    for (int k = 0; k < IN_SIZE / 4; k++) {
        float4 wv = w4[k];
#pragma unroll
        for (int tt = 0; tt < TT; tt++) {
            const float4* xv4 = (const float4*)(xs + tt * IN_SIZE);
            float4 xv = xv4[k];
            acc[tt] = fmaf(wv.x, xv.x, acc[tt]);
            acc[tt] = fmaf(wv.y, xv.y, acc[tt]);
            acc[tt] = fmaf(wv.z, xv.z, acc[tt]);
            acc[tt] = fmaf(wv.w, xv.w, acc[tt]);
        }
    }
#pragma unroll
    for (int tt = 0; tt < TT; tt++)
        ig[(size_t)(t0 + tt) * H3 + j] = acc[tt];
}

// ---------------------------------------------------------------------------
// Kernel B (sequential scan): one workgroup, 384 threads = 6 waves.
// thread tid -> rg = tid>>2 (row group of 4 rows), kseg = tid&3 (32-k slice).
// Each thread holds 4x32 w_hh weights in VGPRs (32 float4s).
// Per step:
//   - matvec: 8 staggered ds_read_b128 of h (4 distinct bank quads per
//     iteration across ksegs) + 128 fma -> 4 row partial sums
//   - one ds_write_b128 of the 4 partials into hgp[kseg][rg]
//   - barrier; threads 0..127 sum 4 partials per gate row (12 b32 reads,
//     lane-consecutive, conflict-free), compute gates, write h, and store
//     hnew[0:32] to global ws (readout deferred to kernel C)
//   - barrier
// Next-step igates prefetched into registers during the matvec.
// ---------------------------------------------------------------------------
__device__ __forceinline__ void fma4(float4& acc, const float4& wv, const float4& hv)
{
    acc.x = fmaf(wv.x, hv.x, acc.x);
    acc.y = fmaf(wv.y, hv.y, acc.y);
    acc.z = fmaf(wv.z, hv.z, acc.z);
    acc.w = fmaf(wv.w, hv.w, acc.w);
}

__global__ __launch_bounds__(384, 2)
void scan_kernel(const float* __restrict__ ig, const float* __restrict__ h0,
                 const float* __restrict__ w_hh, const float* __restrict__ b_n,
                 float* __restrict__ hlin, int T)
{
    __shared__ __align__(16) float h[HID];
    __shared__ __align__(16) float4 hgp[4][100]; // [kseg][rg], slot rg holds rows 4rg..4rg+3

    const int tid = threadIdx.x;     // 0..383
    const int rg = tid >> 2;         // 0..95
    const int kseg = tid & 3;        // 0..3

    // load this thread's 4x32 weight tile into registers
    float4 wr0[8], wr1[8], wr2[8], wr3[8];
    {
        const float* base = w_hh + (size_t)(4 * rg) * HID + kseg * 32;
#pragma unroll
        for (int k = 0; k < 8; k++) {
            wr0[k] = ((const float4*)(base + 0 * HID))[k];
            wr1[k] = ((const float4*)(base + 1 * HID))[k];
            wr2[k] = ((const float4*)(base + 2 * HID))[k];
            wr3[k] = ((const float4*)(base + 3 * HID))[k];
        }
    }
    if (tid < HID) h[tid] = h0[tid];

    float bn = 0.f, ig0 = 0.f, ig1 = 0.f, ig2 = 0.f;
    if (tid < HID) {
        bn = b_n[tid];
        ig0 = ig[tid];
        ig1 = ig[HID + tid];
        ig2 = ig[2 * HID + tid];
    }
    __syncthreads();

    for (int step = 0; step < T; ++step) {
        // prefetch next step's gate inputs (hidden behind the matvec)
        float nig0 = 0.f, nig1 = 0.f, nig2 = 0.f;
        if (step + 1 < T && tid < HID) {
            const float* p = ig + (size_t)(step + 1) * H3;
            nig0 = p[tid];
            nig1 = p[HID + tid];
            nig2 = p[2 * HID + tid];
        }

        // matvec: 4 rows x 32 k per thread, bank-quad staggered h reads
        const float4* h4 = (const float4*)h;
        float4 a0 = {0.f, 0.f, 0.f, 0.f}, a1 = a0, a2 = a0, a3 = a0;
#pragma unroll
        for (int kk = 0; kk < 8; kk++) {
            int k4 = (kk + 2 * kseg) & 7;
            float4 hv = h4[kseg * 8 + k4];
            fma4(a0, wr0[k4], hv);
            fma4(a1, wr1[k4], hv);
            fma4(a2, wr2[k4], hv);
            fma4(a3, wr3[k4], hv);
        }
        float4 s;
        s.x = (a0.x + a0.y) + (a0.z + a0.w);
        s.y = (a1.x + a1.y) + (a1.z + a1.w);
        s.z = (a2.x + a2.y) + (a2.z + a2.w);
        s.w = (a3.x + a3.y) + (a3.z + a3.w);
        hgp[kseg][rg] = s;
        __syncthreads();

        if (tid < HID) {
            // sum the 4 k-slice partials per gate row (plane stride = 400 floats)
            const float* gp = (const float*)hgp;
            float hr = 0.f, hz = 0.f, hn = 0.f;
#pragma unroll
            for (int k = 0; k < 4; k++) {
                const float* p = gp + k * 400;
                hr += p[tid];
                hz += p[HID + tid];
                hn += p[2 * HID + tid];
            }
            float hprev = h[tid];
            float er = __expf(-(ig0 + hr));
            float r = __builtin_amdgcn_rcpf(1.f + er);
            float ez = __expf(-(ig1 + hz));
            float z = __builtin_amdgcn_rcpf(1.f + ez);
            float xn = ig2 + r * (hn + bn);
            float e2 = __expf(-2.f * fabsf(xn));
            float th = (1.f - e2) * __builtin_amdgcn_rcpf(1.f + e2);
            float nn = copysignf(th, xn);
            float hnew = nn + z * (hprev - nn);
            h[tid] = hnew;
            if (tid < LIN_IN)
                hlin[(size_t)step * LIN_IN + tid] = hnew; // fire-and-forget
        }
        ig0 = nig0; ig1 = nig1; ig2 = nig2;
        __syncthreads();
    }
}

// ---------------------------------------------------------------------------
// Kernel C (parallel): out[t] = dot(hlin[t,:], xlin[t,:]) + lbias
// 8 lanes per timestep, float4 loads, 3-stage shfl reduce.
// ---------------------------------------------------------------------------
__global__ __launch_bounds__(256)
void readout_kernel(const float* __restrict__ hlin, const float* __restrict__ xlin,
                    const float* __restrict__ lbias, float* __restrict__ out, int T)
{
    int gid = blockIdx.x * 256 + threadIdx.x;
    int t = gid >> 3;
    int seg = gid & 7;
    if (t < T) {
        float4 hv = ((const float4*)hlin)[(size_t)t * 8 + seg];
        float4 xv = ((const float4*)xlin)[(size_t)t * 8 + seg];
        float p = hv.x * xv.x + hv.y * xv.y + hv.z * xv.z + hv.w * xv.w;
        p += __shfl_xor(p, 1);
        p += __shfl_xor(p, 2);
        p += __shfl_xor(p, 4);
        if (seg == 0) out[t] = p + lbias[0];
    }
}

extern "C" void kernel_launch(void* const* d_in, const int* in_sizes, int n_in,
                              void* d_out, int out_size, void* d_ws, size_t ws_size,
                              hipStream_t stream) {
    const float* x_gru = (const float*)d_in[0];  // (T, 96)
    const float* x_lin = (const float*)d_in[1];  // (T, 32)
    const float* h0    = (const float*)d_in[2];  // (128,)
    const float* w_ih  = (const float*)d_in[3];  // (384, 96)
    const float* w_hh  = (const float*)d_in[4];  // (384, 128)
    const float* b_ih  = (const float*)d_in[5];  // (384,)
    const float* b_n   = (const float*)d_in[6];  // (128,)
    const float* lbias = (const float*)d_in[7];  // (1,)
    float* out = (float*)d_out;                  // (T, 1)

    int T = in_sizes[0] / IN_SIZE;
    float* igates = (float*)d_ws;                    // T*384 floats = 96 MiB
    float* hlin   = (float*)d_ws + (size_t)T * H3;   // T*32 floats  =  8 MiB

    igates_kernel<<<T / 16, 384, 0, stream>>>(x_gru, w_ih, b_ih, igates, T);
    scan_kernel<<<1, 384, 0, stream>>>(igates, h0, w_hh, b_n, hlin, T);
    readout_kernel<<<(T * 8 + 255) / 256, 256, 0, stream>>>(hlin, x_lin, lbias, out, T);
}

// Round 4
// 41778.513 us; speedup vs baseline: 17.1161x; 17.1161x over previous
//
#include <hip/hip_runtime.h>
#include <math.h>

#define IN_SIZE 96
#define HID 128
#define H3 384
#define LIN_IN 32

// ---------------------------------------------------------------------------
// Kernel A (parallel): igates[t][j] = dot(input_GRU[t,:], w_ih[j,:]) + b_ih[j]
// ---------------------------------------------------------------------------
__global__ __launch_bounds__(384, 2)
void igates_kernel(const float* __restrict__ x, const float* __restrict__ w_ih,
                   const float* __restrict__ b_ih, float* __restrict__ ig, int T)
{
    const int TT = 16;
    int t0 = blockIdx.x * TT;
    int j = threadIdx.x; // 0..383
    __shared__ __align__(16) float xs[TT * IN_SIZE]; // 6 KB
    for (int idx = j; idx < TT * IN_SIZE; idx += H3)
        xs[idx] = x[(size_t)t0 * IN_SIZE + idx];
    __syncthreads();

    float acc[TT];
    float b = b_ih[j];
#pragma unroll
    for (int tt = 0; tt < TT; tt++) acc[tt] = b;

    const float4* w4 = (const float4*)(w_ih + (size_t)j * IN_SIZE);
#pragma unroll
    for (int k = 0; k < IN_SIZE / 4; k++) {
        float4 wv = w4[k];
#pragma unroll
        for (int tt = 0; tt < TT; tt++) {
            const float4* xv4 = (const float4*)(xs + tt * IN_SIZE);
            float4 xv = xv4[k];
            acc[tt] = fmaf(wv.x, xv.x, acc[tt]);
            acc[tt] = fmaf(wv.y, xv.y, acc[tt]);
            acc[tt] = fmaf(wv.z, xv.z, acc[tt]);
            acc[tt] = fmaf(wv.w, xv.w, acc[tt]);
        }
    }
#pragma unroll
    for (int tt = 0; tt < TT; tt++)
        ig[(size_t)(t0 + tt) * H3 + j] = acc[tt];
}

// ---------------------------------------------------------------------------
// Kernel B (sequential scan): one workgroup, 384 threads = 6 waves.
// thread tid -> rg = tid>>2 (4-row group), kseg = tid&3 (32-wide k slice).
// 4x32 w_hh weights per thread in VGPRs -- ALL indices literal (SROA-safe;
// the R2 dynamic index k4 spilled everything to scratch: VGPR=56, 9x slower).
// Bank-conflict freedom comes from the PADDED h layout instead:
//   hs[kseg*36 + off], so the 4 concurrent kseg float4 addresses map to
//   banks 4*kseg + 4*kk .. +3  -> disjoint bank quads, conflict-free.
// launch_bounds(384,1): only one block ever runs; full 512-VGPR budget.
// ---------------------------------------------------------------------------
__device__ __forceinline__ void fma4(float4& acc, const float4& wv, const float4& hv)
{
    acc.x = fmaf(wv.x, hv.x, acc.x);
    acc.y = fmaf(wv.y, hv.y, acc.y);
    acc.z = fmaf(wv.z, hv.z, acc.z);
    acc.w = fmaf(wv.w, hv.w, acc.w);
}

#define HPAD 36  // 32 floats per k-segment + 4 pad

__global__ __launch_bounds__(384, 1)
void scan_kernel(const float* __restrict__ ig, const float* __restrict__ h0,
                 const float* __restrict__ w_hh, const float* __restrict__ b_n,
                 float* __restrict__ hlin, int T)
{
    __shared__ __align__(16) float hs[4 * HPAD];   // padded h
    __shared__ __align__(16) float4 hgp[4][100];   // [kseg][rg] partial sums

    const int tid = threadIdx.x;     // 0..383
    const int rg = tid >> 2;         // 0..95
    const int kseg = tid & 3;        // 0..3

    // this thread's 4x32 weight tile -> registers (literal indices only)
    float4 w0[8], w1[8], w2[8], w3[8];
    {
        const float* base = w_hh + (size_t)(4 * rg) * HID + kseg * 32;
#pragma unroll
        for (int k = 0; k < 8; k++) {
            w0[k] = ((const float4*)(base + 0 * HID))[k];
            w1[k] = ((const float4*)(base + 1 * HID))[k];
            w2[k] = ((const float4*)(base + 2 * HID))[k];
            w3[k] = ((const float4*)(base + 3 * HID))[k];
        }
    }
    if (tid < HID) hs[(tid >> 5) * HPAD + (tid & 31)] = h0[tid];

    float bn = 0.f, ig0 = 0.f, ig1 = 0.f, ig2 = 0.f;
    if (tid < HID) {
        bn = b_n[tid];
        ig0 = ig[tid];
        ig1 = ig[HID + tid];
        ig2 = ig[2 * HID + tid];
    }
    __syncthreads();

    const float4* hp = (const float4*)(hs + kseg * HPAD);  // 144B-aligned
    const int hidx = (tid >> 5) * HPAD + (tid & 31);       // gate-thread h slot

    for (int step = 0; step < T; ++step) {
        // prefetch next step's gate inputs (hidden behind the matvec)
        float nig0 = 0.f, nig1 = 0.f, nig2 = 0.f;
        if (step + 1 < T && tid < HID) {
            const float* p = ig + (size_t)(step + 1) * H3;
            nig0 = p[tid];
            nig1 = p[HID + tid];
            nig2 = p[2 * HID + tid];
        }

        // matvec: 4 rows x 32 k per thread, conflict-free padded h reads
        float4 a0 = {0.f, 0.f, 0.f, 0.f}, a1 = a0, a2 = a0, a3 = a0;
#pragma unroll
        for (int kk = 0; kk < 8; kk++) {
            float4 hv = hp[kk];
            fma4(a0, w0[kk], hv);
            fma4(a1, w1[kk], hv);
            fma4(a2, w2[kk], hv);
            fma4(a3, w3[kk], hv);
        }
        float4 s;
        s.x = (a0.x + a0.y) + (a0.z + a0.w);
        s.y = (a1.x + a1.y) + (a1.z + a1.w);
        s.z = (a2.x + a2.y) + (a2.z + a2.w);
        s.w = (a3.x + a3.y) + (a3.z + a3.w);
        hgp[kseg][rg] = s;
        __syncthreads();

        if (tid < HID) {
            // sum the 4 k-slice partials per gate row (plane stride 400 floats)
            const float* gp = (const float*)hgp;
            float hr = 0.f, hz = 0.f, hn = 0.f;
#pragma unroll
            for (int k = 0; k < 4; k++) {
                const float* p = gp + k * 400;
                hr += p[tid];
                hz += p[HID + tid];
                hn += p[2 * HID + tid];
            }
            float hprev = hs[hidx];
            float er = __expf(-(ig0 + hr));
            float r = __builtin_amdgcn_rcpf(1.f + er);
            float ez = __expf(-(ig1 + hz));
            float z = __builtin_amdgcn_rcpf(1.f + ez);
            float xn = ig2 + r * (hn + bn);
            float e2 = __expf(-2.f * fabsf(xn));
            float th = (1.f - e2) * __builtin_amdgcn_rcpf(1.f + e2);
            float nn = copysignf(th, xn);
            float hnew = nn + z * (hprev - nn);
            hs[hidx] = hnew;
            if (tid < LIN_IN)
                hlin[(size_t)step * LIN_IN + tid] = hnew; // readout deferred
        }
        ig0 = nig0; ig1 = nig1; ig2 = nig2;
        __syncthreads();
    }
}

// ---------------------------------------------------------------------------
// Kernel C (parallel): out[t] = dot(hlin[t,:], xlin[t,:]) + lbias
// ---------------------------------------------------------------------------
__global__ __launch_bounds__(256)
void readout_kernel(const float* __restrict__ hlin, const float* __restrict__ xlin,
                    const float* __restrict__ lbias, float* __restrict__ out, int T)
{
    int gid = blockIdx.x * 256 + threadIdx.x;
    int t = gid >> 3;
    int seg = gid & 7;
    if (t < T) {
        float4 hv = ((const float4*)hlin)[(size_t)t * 8 + seg];
        float4 xv = ((const float4*)xlin)[(size_t)t * 8 + seg];
        float p = hv.x * xv.x + hv.y * xv.y + hv.z * xv.z + hv.w * xv.w;
        p += __shfl_xor(p, 1);
        p += __shfl_xor(p, 2);
        p += __shfl_xor(p, 4);
        if (seg == 0) out[t] = p + lbias[0];
    }
}

extern "C" void kernel_launch(void* const* d_in, const int* in_sizes, int n_in,
                              void* d_out, int out_size, void* d_ws, size_t ws_size,
                              hipStream_t stream) {
    const float* x_gru = (const float*)d_in[0];  // (T, 96)
    const float* x_lin = (const float*)d_in[1];  // (T, 32)
    const float* h0    = (const float*)d_in[2];  // (128,)
    const float* w_ih  = (const float*)d_in[3];  // (384, 96)
    const float* w_hh  = (const float*)d_in[4];  // (384, 128)
    const float* b_ih  = (const float*)d_in[5];  // (384,)
    const float* b_n   = (const float*)d_in[6];  // (128,)
    const float* lbias = (const float*)d_in[7];  // (1,)
    float* out = (float*)d_out;                  // (T, 1)

    int T = in_sizes[0] / IN_SIZE;
    float* igates = (float*)d_ws;                    // T*384 floats = 96 MiB
    float* hlin   = (float*)d_ws + (size_t)T * H3;   // T*32 floats  =  8 MiB

    igates_kernel<<<T / 16, 384, 0, stream>>>(x_gru, w_ih, b_ih, igates, T);
    scan_kernel<<<1, 384, 0, stream>>>(igates, h0, w_hh, b_n, hlin, T);
    readout_kernel<<<(T * 8 + 255) / 256, 256, 0, stream>>>(hlin, x_lin, lbias, out, T);
}